// Round 3
// baseline (641.681 us; speedup 1.0000x reference)
//
#include <hip/hip_runtime.h>
#include <stdint.h>

#define NN 100000
#define EE 1600000
#define FEAT 32
#define HID 64
#define MSG 32
#define GOALD 16
#define OUTD 8
#define UPD_IN 112
#define EPS 1e-5f

typedef float f32x2 __attribute__((ext_vector_type(2)));

// ---------- K1: column stats of x1 = relu(nodes@W_in + b_in) (x1 not stored) ----------
__global__ __launch_bounds__(256) void k_in_stats(
    const float* __restrict__ nodes, const float* __restrict__ W_in,
    const float* __restrict__ b_in, float* __restrict__ stats1)
{
    __shared__ float red[256];
    const int tid = threadIdx.x;
    const int j = tid & 63, slot = tid >> 6;
    float w[FEAT];
#pragma unroll
    for (int k = 0; k < FEAT; ++k) w[k] = W_in[k * HID + j];
    const float bj = b_in[j];
    float lsum = 0.f, lsq = 0.f;
    for (int i = blockIdx.x * 4 + slot; i < NN; i += gridDim.x * 4) {
        const float4* row = (const float4*)(nodes + (size_t)i * FEAT);
        float acc = bj;
#pragma unroll
        for (int q = 0; q < FEAT / 4; ++q) {
            float4 r = row[q];
            acc = fmaf(r.x, w[q * 4 + 0], acc);
            acc = fmaf(r.y, w[q * 4 + 1], acc);
            acc = fmaf(r.z, w[q * 4 + 2], acc);
            acc = fmaf(r.w, w[q * 4 + 3], acc);
        }
        float v = fmaxf(acc, 0.f);
        lsum += v; lsq += v * v;
    }
    red[tid] = lsum; __syncthreads();
    if (tid < 64) atomicAdd(&stats1[tid], red[tid] + red[tid + 64] + red[tid + 128] + red[tid + 192]);
    __syncthreads();
    red[tid] = lsq; __syncthreads();
    if (tid < 64) atomicAdd(&stats1[64 + tid], red[tid] + red[tid + 64] + red[tid + 128] + red[tid + 192]);
}

// ---------- K2: h = BN1(relu(nodes@W_in+b)) stored; x2 = relu(h@W_msg+b) stored; stats2 ----------
__global__ __launch_bounds__(256) void k_h_msg(
    const float* __restrict__ nodes, const float* __restrict__ W_in,
    const float* __restrict__ b_in, const float* __restrict__ stats1,
    const float* __restrict__ g_in, const float* __restrict__ be_in,
    const float* __restrict__ W_msg, const float* __restrict__ b_msg,
    float* __restrict__ h_out, float* __restrict__ x2_out,
    float* __restrict__ stats2)
{
    __shared__ float shh[4][HID];
    __shared__ float red[256];
    const int tid = threadIdx.x;
    const int j = tid & 63, slot = tid >> 6;
    const int j2 = j & 31, half = j >> 5;
    float w[FEAT];
#pragma unroll
    for (int k = 0; k < FEAT; ++k) w[k] = W_in[k * HID + j];
    float wm[32];
#pragma unroll
    for (int k = 0; k < 32; ++k) wm[k] = W_msg[(half * 32 + k) * MSG + j2];
    const float bj = b_in[j];
    // inline BN1 finalize from raw stats
    const float m1 = stats1[j] * (1.f / NN);
    const float va1 = stats1[HID + j] * (1.f / NN) - m1 * m1;
    const float s1 = g_in[j] * rsqrtf(va1 + EPS);
    const float t1 = be_in[j] - m1 * s1;
    const float bm = b_msg[j2];
    float lsum = 0.f, lsq = 0.f;
    for (int base = blockIdx.x * 4; base < NN; base += gridDim.x * 4) {
        const int i = base + slot;
        const bool act = i < NN;
        float hv = 0.f;
        if (act) {
            const float4* row = (const float4*)(nodes + (size_t)i * FEAT);
            float acc = bj;
#pragma unroll
            for (int q = 0; q < FEAT / 4; ++q) {
                float4 r = row[q];
                acc = fmaf(r.x, w[q * 4 + 0], acc);
                acc = fmaf(r.y, w[q * 4 + 1], acc);
                acc = fmaf(r.z, w[q * 4 + 2], acc);
                acc = fmaf(r.w, w[q * 4 + 3], acc);
            }
            hv = fmaf(fmaxf(acc, 0.f), s1, t1);
            h_out[(size_t)i * HID + j] = hv;
        }
        shh[slot][j] = hv;
        __syncthreads();
        if (act) {
            const float4* hr = (const float4*)(&shh[slot][half * 32]);
            float acc2 = 0.f;
#pragma unroll
            for (int q = 0; q < 8; ++q) {
                float4 r = hr[q];
                acc2 = fmaf(r.x, wm[q * 4 + 0], acc2);
                acc2 = fmaf(r.y, wm[q * 4 + 1], acc2);
                acc2 = fmaf(r.z, wm[q * 4 + 2], acc2);
                acc2 = fmaf(r.w, wm[q * 4 + 3], acc2);
            }
            acc2 += __shfl_xor(acc2, 32);
            if (half == 0) {
                float v = fmaxf(acc2 + bm, 0.f);
                x2_out[(size_t)i * MSG + j2] = v;
                lsum += v; lsq += v * v;
            }
        }
        __syncthreads();
    }
    red[tid] = (half == 0) ? lsum : 0.f; __syncthreads();
    if (tid < 32) atomicAdd(&stats2[tid], red[tid] + red[tid + 64] + red[tid + 128] + red[tid + 192]);
    __syncthreads();
    red[tid] = (half == 0) ? lsq : 0.f; __syncthreads();
    if (tid < 32) atomicAdd(&stats2[32 + tid], red[tid] + red[tid + 64] + red[tid + 128] + red[tid + 192]);
}

// ---------- K3: edge scatter: agg[dst] += BN2(x2[src]) with packed f32 atomics ----------
__global__ __launch_bounds__(256) void k_edges(
    const int* __restrict__ esrc, const int* __restrict__ edst,
    const float* __restrict__ x2, const float* __restrict__ stats2,
    const float* __restrict__ g_msg, const float* __restrict__ be_msg,
    float* __restrict__ agg)
{
    const int c0 = (threadIdx.x & 15) << 1;  // channel pair {c0, c0+1}
    const float m0 = stats2[c0] * (1.f / NN);
    const float m1 = stats2[c0 + 1] * (1.f / NN);
    const float va0 = stats2[MSG + c0] * (1.f / NN) - m0 * m0;
    const float va1 = stats2[MSG + c0 + 1] * (1.f / NN) - m1 * m1;
    const float s0 = g_msg[c0] * rsqrtf(va0 + EPS);
    const float s1 = g_msg[c0 + 1] * rsqrtf(va1 + EPS);
    const float t0 = be_msg[c0] - m0 * s0;
    const float t1 = be_msg[c0 + 1] - m1 * s1;
    const int total = EE * 16;
    const int stride = gridDim.x * blockDim.x;
    for (int idx = blockIdx.x * blockDim.x + threadIdx.x; idx < total; idx += stride) {
        const int e = idx >> 4;
        const int si = esrc[e], di = edst[e];
        const f32x2 v = *(const f32x2*)(x2 + (size_t)si * MSG + c0);
        f32x2 d;
        d.x = fmaf(v.x, s0, t0);
        d.y = fmaf(v.y, s1, t1);
        float* p = agg + (size_t)di * MSG + c0;
#if __has_builtin(__builtin_amdgcn_global_atomic_fadd_v2f32)
        typedef __attribute__((address_space(1))) f32x2 f32x2_g;
        __builtin_amdgcn_global_atomic_fadd_v2f32((f32x2_g*)(uintptr_t)p, d);
#else
        atomicAdd(p, d.x);
        atomicAdd(p + 1, d.y);
#endif
    }
}

// ---------- K4: x3 = relu([agg,h,goal]@W_upd + b) -> d_out u-region; stats3 ----------
__global__ __launch_bounds__(256) void k_upd(
    const float* __restrict__ agg, const float* __restrict__ h,
    const float* __restrict__ goal, const float* __restrict__ W_upd,
    const float* __restrict__ b_upd, float* __restrict__ x3_out,
    float* __restrict__ stats3)
{
    __shared__ float cat[4][UPD_IN];
    __shared__ float red[256];
    const int tid = threadIdx.x;
    const int j = tid & 63, slot = tid >> 6;
    float w[UPD_IN];
#pragma unroll
    for (int k = 0; k < UPD_IN; ++k) w[k] = W_upd[k * HID + j];
    const float bj = b_upd[j];
    float lsum = 0.f, lsq = 0.f;
    for (int base = blockIdx.x * 4; base < NN; base += gridDim.x * 4) {
        const int i = base + slot;
        const bool act = i < NN;
        if (act) {
            if (j < 32) cat[slot][j] = agg[(size_t)i * MSG + j];
            cat[slot][32 + j] = h[(size_t)i * HID + j];
            if (j < 16) cat[slot][96 + j] = goal[(size_t)i * GOALD + j];
        }
        __syncthreads();
        if (act) {
            const float4* cr = (const float4*)cat[slot];
            float acc = bj;
#pragma unroll
            for (int q = 0; q < UPD_IN / 4; ++q) {
                float4 r = cr[q];
                acc = fmaf(r.x, w[q * 4 + 0], acc);
                acc = fmaf(r.y, w[q * 4 + 1], acc);
                acc = fmaf(r.z, w[q * 4 + 2], acc);
                acc = fmaf(r.w, w[q * 4 + 3], acc);
            }
            float v = fmaxf(acc, 0.f);
            x3_out[(size_t)i * HID + j] = v;
            lsum += v; lsq += v * v;
        }
        __syncthreads();
    }
    red[tid] = lsum; __syncthreads();
    if (tid < 64) atomicAdd(&stats3[tid], red[tid] + red[tid + 64] + red[tid + 128] + red[tid + 192]);
    __syncthreads();
    red[tid] = lsq; __syncthreads();
    if (tid < 64) atomicAdd(&stats3[64 + tid], red[tid] + red[tid + 64] + red[tid + 128] + red[tid + 192]);
}

// ---------- K5: u = BN3(x3) in-place in d_out; out = u@W_out + b_out ----------
__global__ __launch_bounds__(256) void k_out(
    float* __restrict__ x3u, const float* __restrict__ stats3,
    const float* __restrict__ g_upd, const float* __restrict__ be_upd,
    const float* __restrict__ W_out, const float* __restrict__ b_out,
    float* __restrict__ o_out)
{
    __shared__ float shu[4][HID];
    const int tid = threadIdx.x;
    const int j = tid & 63, slot = tid >> 6;
    const int o = j & 7, part = j >> 3;
    const float m3 = stats3[j] * (1.f / NN);
    const float va3 = stats3[HID + j] * (1.f / NN) - m3 * m3;
    const float s3 = g_upd[j] * rsqrtf(va3 + EPS);
    const float t3 = be_upd[j] - m3 * s3;
    float w[8];
#pragma unroll
    for (int k = 0; k < 8; ++k) w[k] = W_out[(part * 8 + k) * OUTD + o];
    const float bo = b_out[o];
    for (int base = blockIdx.x * 4; base < NN; base += gridDim.x * 4) {
        const int i = base + slot;
        const bool act = i < NN;
        float u = 0.f;
        if (act) {
            u = fmaf(x3u[(size_t)i * HID + j], s3, t3);
            x3u[(size_t)i * HID + j] = u;
        }
        shu[slot][j] = u;
        __syncthreads();
        if (act) {
            const float* ur = &shu[slot][part * 8];
            float acc = 0.f;
#pragma unroll
            for (int k = 0; k < 8; ++k) acc = fmaf(ur[k], w[k], acc);
            acc += __shfl_xor(acc, 8);
            acc += __shfl_xor(acc, 16);
            acc += __shfl_xor(acc, 32);
            if (part == 0) o_out[(size_t)i * OUTD + o] = acc + bo;
        }
        __syncthreads();
    }
}

extern "C" void kernel_launch(void* const* d_in, const int* in_sizes, int n_in,
                              void* d_out, int out_size, void* d_ws, size_t ws_size,
                              hipStream_t stream)
{
    (void)in_sizes; (void)n_in; (void)out_size;
    const float* nodes  = (const float*)d_in[0];
    const float* goal   = (const float*)d_in[1];
    const int*   esrc   = (const int*)d_in[2];
    const int*   edst   = (const int*)d_in[3];
    const float* W_in   = (const float*)d_in[6];
    const float* b_in   = (const float*)d_in[7];
    const float* g_in   = (const float*)d_in[8];
    const float* be_in  = (const float*)d_in[9];
    const float* W_msg  = (const float*)d_in[10];
    const float* b_msg  = (const float*)d_in[11];
    const float* g_msg  = (const float*)d_in[12];
    const float* be_msg = (const float*)d_in[13];
    const float* W_upd  = (const float*)d_in[14];
    const float* b_upd  = (const float*)d_in[15];
    const float* g_upd  = (const float*)d_in[16];
    const float* be_upd = (const float*)d_in[17];
    const float* W_out  = (const float*)d_in[18];
    const float* b_out  = (const float*)d_in[19];

    // Workspace: stats (320 floats) then h (N*64), x2 (N*32), agg (N*32)
    const size_t need = ((size_t)NN * 128 + 320) * sizeof(float);
    if (ws_size < need) return;  // fail soft instead of OOB-faulting

    float* st = (float*)d_ws;
    float* stats1 = st;        // 128
    float* stats2 = st + 128;  // 64
    float* stats3 = st + 192;  // 128
    float* h   = st + 320;                 // N*64
    float* x2  = h + (size_t)NN * 64;      // N*32
    float* agg = x2 + (size_t)NN * 32;     // N*32

    float* u_out = (float*)d_out;                    // N*64 (x3, then u in-place)
    float* o_out = (float*)d_out + (size_t)NN * HID; // N*8

    hipMemsetAsync(st, 0, 320 * sizeof(float), stream);
    hipMemsetAsync(agg, 0, (size_t)NN * MSG * sizeof(float), stream);

    k_in_stats<<<1024, 256, 0, stream>>>(nodes, W_in, b_in, stats1);
    k_h_msg<<<1024, 256, 0, stream>>>(nodes, W_in, b_in, stats1, g_in, be_in,
                                      W_msg, b_msg, h, x2, stats2);
    k_edges<<<4096, 256, 0, stream>>>(esrc, edst, x2, stats2, g_msg, be_msg, agg);
    k_upd<<<1024, 256, 0, stream>>>(agg, h, goal, W_upd, b_upd, u_out, stats3);
    k_out<<<1024, 256, 0, stream>>>(u_out, stats3, g_upd, be_upd, W_out, b_out, o_out);
}